// Round 1
// baseline (232.073 us; speedup 1.0000x reference)
//
#include <hip/hip_runtime.h>

// Performer exp-kernel linear causal attention.
// B=4, H=8, N=2048, D=64, fp32.
// Chunked linear-attention decomposition:
//   k0: per-(b,h) max of k
//   k1: per-chunk partial KV (64x64) and Ksum (64)
//   k2: in-place exclusive prefix scan over chunks (per b,h)
//   k3: per-chunk output = q.KV_prefix + causal-intra (QK^T masked)@V, / denom

#define NSEQ 2048
#define DD 64
#define CH 128
#define NC (NSEQ / CH)   // 16
#define BHN 32
#define EPSF 1e-8f
#define NRM 0.35355339059327373f   // 64^(-0.25)

// ---------------- kernel 0: per-(b,h) max of k ----------------
__global__ __launch_bounds__(256) void k0_kmax(const float* __restrict__ k,
                                               float* __restrict__ kmax) {
  int bh = blockIdx.x;
  const float4* kp = (const float4*)(k + (size_t)bh * (NSEQ * DD));
  int t = threadIdx.x;
  float m = -1e30f;
#pragma unroll 8
  for (int r = 0; r < 128; ++r) {
    float4 x = kp[t + 256 * r];
    m = fmaxf(m, fmaxf(fmaxf(x.x, x.y), fmaxf(x.z, x.w)));
  }
#pragma unroll
  for (int off = 32; off > 0; off >>= 1)
    m = fmaxf(m, __shfl_down(m, off, 64));
  __shared__ float red[4];
  if ((t & 63) == 0) red[t >> 6] = m;
  __syncthreads();
  if (t == 0)
    kmax[bh] = fmaxf(fmaxf(red[0], red[1]), fmaxf(red[2], red[3]));
}

// ---------------- kernel 1: per-chunk partial KV and Ksum ----------------
__global__ __launch_bounds__(256) void k1_partial(const float* __restrict__ k,
                                                  const float* __restrict__ v,
                                                  const float* __restrict__ kmaxp,
                                                  float* __restrict__ ksum_part,
                                                  float* __restrict__ kv_part) {
  __shared__ float klds[CH * DD];   // 32 KB
  __shared__ float vlds[CH * DD];   // 32 KB
  const int blk = blockIdx.x;
  const int bh = blk / NC, c = blk % NC;
  const float km = kmaxp[bh];
  const size_t base = ((size_t)bh * NSEQ + (size_t)c * CH) * DD;
  const float4* k4 = (const float4*)(k + base);
  const float4* v4 = (const float4*)(v + base);
  const int t = threadIdx.x;
#pragma unroll
  for (int r = 0; r < 8; ++r) {
    int i = t + 256 * r;
    float4 kk = k4[i];
    kk.x = __expf(NRM * (kk.x - km)) + EPSF;
    kk.y = __expf(NRM * (kk.y - km)) + EPSF;
    kk.z = __expf(NRM * (kk.z - km)) + EPSF;
    kk.w = __expf(NRM * (kk.w - km)) + EPSF;
    ((float4*)klds)[i] = kk;
    ((float4*)vlds)[i] = v4[i];
  }
  __syncthreads();
  const int e = t >> 2, fq = t & 3;
  float4 a0 = {0,0,0,0}, a1 = {0,0,0,0}, a2 = {0,0,0,0}, a3 = {0,0,0,0};
  for (int n = 0; n < CH; ++n) {
    float ke = klds[n * DD + e];
    const float4* vr = (const float4*)(vlds + n * DD) + fq * 4;
    float4 v0 = vr[0], v1 = vr[1], v2 = vr[2], v3 = vr[3];
    a0.x += ke * v0.x; a0.y += ke * v0.y; a0.z += ke * v0.z; a0.w += ke * v0.w;
    a1.x += ke * v1.x; a1.y += ke * v1.y; a1.z += ke * v1.z; a1.w += ke * v1.w;
    a2.x += ke * v2.x; a2.y += ke * v2.y; a2.z += ke * v2.z; a2.w += ke * v2.w;
    a3.x += ke * v3.x; a3.y += ke * v3.y; a3.z += ke * v3.z; a3.w += ke * v3.w;
  }
  float4* kvout = (float4*)(kv_part + (size_t)blk * (DD * DD) + e * DD + fq * 16);
  kvout[0] = a0; kvout[1] = a1; kvout[2] = a2; kvout[3] = a3;
  if (t < DD) {
    float s = 0.f;
    for (int n = 0; n < CH; ++n) s += klds[n * DD + t];
    ksum_part[(size_t)blk * DD + t] = s;
  }
}

// ---------------- kernel 2: in-place exclusive scan over chunks ----------------
__global__ __launch_bounds__(256) void k2_scan(float* __restrict__ ksum_part,
                                               float* __restrict__ kv_part) {
  const int bh = blockIdx.x;
  const int t = threadIdx.x;
  float run[16];
#pragma unroll
  for (int r = 0; r < 16; ++r) run[r] = 0.f;
  float runk = 0.f;
  for (int c = 0; c < NC; ++c) {
    float* kvb = kv_part + ((size_t)bh * NC + c) * (DD * DD);
#pragma unroll
    for (int r = 0; r < 16; ++r) {
      int i = t + 256 * r;
      float x = kvb[i];
      kvb[i] = run[r];
      run[r] += x;
    }
    if (t < DD) {
      float* ks = ksum_part + ((size_t)bh * NC + c) * DD;
      float x = ks[t];
      ks[t] = runk;
      runk += x;
    }
  }
}

// ---------------- kernel 3: per-chunk output ----------------
// 256 threads: 2 threads per row (each owns half the 64 feature dims).
__global__ __launch_bounds__(256) void k3_out(const float* __restrict__ q,
                                              const float* __restrict__ k,
                                              const float* __restrict__ v,
                                              const float* __restrict__ kmaxp,
                                              const float* __restrict__ ksum_pref,
                                              const float* __restrict__ kv_pref,
                                              float* __restrict__ out) {
  __shared__ float klds[CH * DD];   // 32 KB
  __shared__ float vlds[CH * DD];   // 32 KB
  __shared__ float kvp[DD * DD];    // 16 KB  -> 80 KB total => 2 blocks/CU
  const int blk = blockIdx.x;
  const int bh = blk / NC, c = blk % NC;
  const int t = threadIdx.x;
  const int row = t >> 1;   // 0..127
  const int h = t & 1;      // which half of the 64 dims
  const float km = kmaxp[bh];
  const size_t cbase = ((size_t)bh * NSEQ + (size_t)c * CH) * DD;

  const float4* k4 = (const float4*)(k + cbase);
  const float4* v4 = (const float4*)(v + cbase);
#pragma unroll
  for (int r = 0; r < 8; ++r) {
    int i = t + 256 * r;
    float4 kk = k4[i];
    kk.x = __expf(NRM * (kk.x - km)) + EPSF;
    kk.y = __expf(NRM * (kk.y - km)) + EPSF;
    kk.z = __expf(NRM * (kk.z - km)) + EPSF;
    kk.w = __expf(NRM * (kk.w - km)) + EPSF;
    ((float4*)klds)[i] = kk;
    ((float4*)vlds)[i] = v4[i];
  }
  const float4* kvg = (const float4*)(kv_pref + (size_t)blk * (DD * DD));
#pragma unroll
  for (int r = 0; r < 4; ++r) {
    int i = t + 256 * r;
    ((float4*)kvp)[i] = kvg[i];
  }

  // q half-row -> registers, then stabilize+exp
  float4 qr[8];
  const float4* qrow = (const float4*)(q + cbase + (size_t)row * DD + (size_t)h * 32);
#pragma unroll
  for (int r = 0; r < 8; ++r) qr[r] = qrow[r];
  float qm = -1e30f;
#pragma unroll
  for (int r = 0; r < 8; ++r)
    qm = fmaxf(qm, fmaxf(fmaxf(qr[r].x, qr[r].y), fmaxf(qr[r].z, qr[r].w)));
  qm = fmaxf(qm, __shfl_xor(qm, 1));   // full-row max
#pragma unroll
  for (int r = 0; r < 8; ++r) {
    qr[r].x = __expf(NRM * (qr[r].x - qm)) + EPSF;
    qr[r].y = __expf(NRM * (qr[r].y - qm)) + EPSF;
    qr[r].z = __expf(NRM * (qr[r].z - qm)) + EPSF;
    qr[r].w = __expf(NRM * (qr[r].w - qm)) + EPSF;
  }
  __syncthreads();

  float4 acc[8];
#pragma unroll
  for (int r = 0; r < 8; ++r) acc[r] = make_float4(0.f, 0.f, 0.f, 0.f);

  // prefix part: acc[f] += sum_e q[e]*KVp[e][f]  (f in own half, e over all 64)
  const float* ksp = ksum_pref + (size_t)blk * DD;
  float dhalf = 0.f, shalf = 0.f;
#pragma unroll
  for (int e4 = 0; e4 < 8; ++e4) {
    float qe[4] = {qr[e4].x, qr[e4].y, qr[e4].z, qr[e4].w};
#pragma unroll
    for (int l = 0; l < 4; ++l) {
      float qo = qe[l];                  // own-half q value
      float qp = __shfl_xor(qo, 1);      // partner-half q value
      int e_own = h * 32 + e4 * 4 + l;
      int e_oth = (h ^ 1) * 32 + e4 * 4 + l;
      shalf += qo;
      dhalf += qo * ksp[e_own];
      const float4* r0 = (const float4*)(kvp + e_own * DD + h * 32);
      const float4* r1 = (const float4*)(kvp + e_oth * DD + h * 32);
#pragma unroll
      for (int f4 = 0; f4 < 8; ++f4) {
        float4 x = r0[f4];
        acc[f4].x += qo * x.x; acc[f4].y += qo * x.y;
        acc[f4].z += qo * x.z; acc[f4].w += qo * x.w;
      }
#pragma unroll
      for (int f4 = 0; f4 < 8; ++f4) {
        float4 x = r1[f4];
        acc[f4].x += qp * x.x; acc[f4].y += qp * x.y;
        acc[f4].z += qp * x.z; acc[f4].w += qp * x.w;
      }
    }
  }
  float denom = dhalf + __shfl_xor(dhalf, 1);
  float sq = shalf + __shfl_xor(shalf, 1);
  denom += EPSF * sq;

  // causal intra-chunk: wave-uniform bound (rows per wave: 32)
  const int jend = row | 31;
  for (int j = 0; j <= jend; ++j) {
    const float4* kr = (const float4*)(klds + j * DD + h * 32);
    float part = 0.f;
#pragma unroll
    for (int e4 = 0; e4 < 8; ++e4) {
      float4 kk = kr[e4];
      part += qr[e4].x * kk.x + qr[e4].y * kk.y + qr[e4].z * kk.z + qr[e4].w * kk.w;
    }
    float a = part + __shfl_xor(part, 1);   // full 64-dot
    if (j <= row) {
      denom += a;
      const float4* vr = (const float4*)(vlds + j * DD + h * 32);
#pragma unroll
      for (int f4 = 0; f4 < 8; ++f4) {
        float4 vv = vr[f4];
        acc[f4].x += a * vv.x; acc[f4].y += a * vv.y;
        acc[f4].z += a * vv.z; acc[f4].w += a * vv.w;
      }
    }
  }

  const float dinv = 1.0f / denom;
  float4* op = (float4*)(out + cbase + (size_t)row * DD + (size_t)h * 32);
#pragma unroll
  for (int f4 = 0; f4 < 8; ++f4) {
    float4 o;
    o.x = acc[f4].x * dinv; o.y = acc[f4].y * dinv;
    o.z = acc[f4].z * dinv; o.w = acc[f4].w * dinv;
    op[f4] = o;
  }
}

extern "C" void kernel_launch(void* const* d_in, const int* in_sizes, int n_in,
                              void* d_out, int out_size, void* d_ws, size_t ws_size,
                              hipStream_t stream) {
  const float* q = (const float*)d_in[0];
  const float* k = (const float*)d_in[1];
  const float* v = (const float*)d_in[2];
  float* out = (float*)d_out;
  float* ws = (float*)d_ws;
  // workspace layout (floats): kmax[32] | ksum[32*16*64] | kv[32*16*4096]  (~8.5 MB)
  float* kmax = ws;
  float* ksum = ws + 32;
  float* kvp  = ws + 32 + (size_t)BHN * NC * DD;

  hipLaunchKernelGGL(k0_kmax, dim3(BHN), dim3(256), 0, stream, k, kmax);
  hipLaunchKernelGGL(k1_partial, dim3(BHN * NC), dim3(256), 0, stream, k, v, kmax, ksum, kvp);
  hipLaunchKernelGGL(k2_scan, dim3(BHN), dim3(256), 0, stream, ksum, kvp);
  hipLaunchKernelGGL(k3_out, dim3(BHN * NC), dim3(256), 0, stream, q, k, v, kmax, ksum, kvp, out);
}

// Round 3
// 114.814 us; speedup vs baseline: 2.0213x; 2.0213x over previous
//
#include <hip/hip_runtime.h>

// Performer exp-kernel linear causal attention, MFMA bf16 version.
// B=4 H=8 N=2048 D=64 fp32 in/out.
// k0a: partial max of k (256 blocks)           -> partmax[256]
// k1 : per-chunk KV^T partials (bf16) + Ksum   (1024 blocks, MFMA)
// k2 : exclusive prefix scan over 32 chunks    (288 blocks)
// k3 : out = (Q'.KVpref + masked(Q'K'^T).V) / denom  (1024 blocks, MFMA)

#define NSEQ 2048
#define DD 64
#define CH 64
#define NC (NSEQ / CH)   // 32
#define BHN 32
#define EPSF 1e-8f
#define NRM 0.35355339059327373f   // 64^(-0.25)

typedef short bf16x8 __attribute__((ext_vector_type(8)));
typedef float f32x4 __attribute__((ext_vector_type(4)));

__device__ __forceinline__ unsigned short f2bf(float f) {
  union { float f; unsigned u; } c; c.f = f;
  unsigned u = c.u + 0x7fffu + ((c.u >> 16) & 1u);
  return (unsigned short)(u >> 16);
}
__device__ __forceinline__ float bf2f(unsigned short s) {
  union { unsigned u; float f; } c; c.u = ((unsigned)s) << 16;
  return c.f;
}

// ---------------- k0a: partial max of k ----------------
__global__ __launch_bounds__(256) void k0a_max(const float* __restrict__ k,
                                               float* __restrict__ partmax) {
  const int blk = blockIdx.x;           // bh*8 + part, 256 total
  const float4* kp = (const float4*)(k + (size_t)blk * 16384);
  const int t = threadIdx.x;
  float m = -1e30f;
#pragma unroll
  for (int r = 0; r < 16; ++r) {
    float4 x = kp[t + 256 * r];
    m = fmaxf(m, fmaxf(fmaxf(x.x, x.y), fmaxf(x.z, x.w)));
  }
#pragma unroll
  for (int off = 32; off > 0; off >>= 1)
    m = fmaxf(m, __shfl_xor(m, off, 64));
  __shared__ float red[4];
  if ((t & 63) == 0) red[t >> 6] = m;
  __syncthreads();
  if (t == 0)
    partmax[blk] = fmaxf(fmaxf(red[0], red[1]), fmaxf(red[2], red[3]));
}

__device__ __forceinline__ float load_km(const float* __restrict__ partmax, int bh) {
  float km = partmax[bh * 8];
#pragma unroll
  for (int i = 1; i < 8; ++i) km = fmaxf(km, partmax[bh * 8 + i]);
  return km;
}

// ---------------- k1: per-chunk KV partial (bf16) + Ksum ----------------
__global__ __launch_bounds__(256) void k1_partial(const float* __restrict__ kg,
                                                  const float* __restrict__ vg,
                                                  const float* __restrict__ partmax,
                                                  float* __restrict__ ksum,
                                                  unsigned short* __restrict__ kvws) {
  __shared__ __align__(16) unsigned short Kt[DD * 72];   // K'^T  [e][j]
  __shared__ __align__(16) unsigned short Vt[DD * 72];   // V^T   [f][j]
  const int blk = blockIdx.x;
  const int bh = blk >> 5, c = blk & 31;
  const float km = load_km(partmax, bh);
  const float c1 = NRM * 1.4426950408889634f;
  const float c2 = -km * c1;
  const int t = threadIdx.x;
  const size_t base = ((size_t)bh * NSEQ + (size_t)c * CH) * DD;
  const float4* k4 = (const float4*)(kg + base);
  const float4* v4 = (const float4*)(vg + base);
#pragma unroll
  for (int r = 0; r < 4; ++r) {
    int idx4 = t + 256 * r;
    int j = idx4 >> 4, e0 = (idx4 & 15) << 2;
    float4 kk = k4[idx4];
    float kv0[4] = {kk.x, kk.y, kk.z, kk.w};
    float4 vv = v4[idx4];
    float vv0[4] = {vv.x, vv.y, vv.z, vv.w};
#pragma unroll
    for (int i = 0; i < 4; ++i) {
      Kt[(e0 + i) * 72 + j] = f2bf(exp2f(kv0[i] * c1 + c2) + EPSF);
      Vt[(e0 + i) * 72 + j] = f2bf(vv0[i]);
    }
  }
  __syncthreads();
  const int wr = t >> 6, l = t & 63, lg = l >> 4, lc = l & 15;
  // A fragments: rows e = wr*16+lc, k = j
  bf16x8 a0 = *(const bf16x8*)&Kt[(wr * 16 + lc) * 72 + lg * 8];
  bf16x8 a1 = *(const bf16x8*)&Kt[(wr * 16 + lc) * 72 + 32 + lg * 8];
  // Ksum over j of K'[j][e]: this lane holds 16 j-values of row e
  float ks = 0.f;
#pragma unroll
  for (int i = 0; i < 8; ++i) ks += bf2f((unsigned short)a0[i]) + bf2f((unsigned short)a1[i]);
  ks += __shfl_xor(ks, 16, 64);
  ks += __shfl_xor(ks, 32, 64);
  if (lg == 0) ksum[(size_t)blk * DD + wr * 16 + lc] = ks;
  // KV = K'^T @ V
  f32x4 acc[4];
#pragma unroll
  for (int ft = 0; ft < 4; ++ft) { acc[ft] = (f32x4){0.f, 0.f, 0.f, 0.f}; }
#pragma unroll
  for (int ft = 0; ft < 4; ++ft) {
    bf16x8 b0 = *(const bf16x8*)&Vt[(ft * 16 + lc) * 72 + lg * 8];
    bf16x8 b1 = *(const bf16x8*)&Vt[(ft * 16 + lc) * 72 + 32 + lg * 8];
    acc[ft] = __builtin_amdgcn_mfma_f32_16x16x32_bf16(a0, b0, acc[ft], 0, 0, 0);
    acc[ft] = __builtin_amdgcn_mfma_f32_16x16x32_bf16(a1, b1, acc[ft], 0, 0, 0);
  }
  // store f-major bf16: ws[blk][f][e]; rows e = wr*16 + lg*4 + reg (4 consecutive)
  unsigned short* kvb = kvws + (size_t)blk * (DD * DD);
  const int e0 = wr * 16 + lg * 4;
#pragma unroll
  for (int ft = 0; ft < 4; ++ft) {
    short4 w;
    w.x = (short)f2bf(acc[ft][0]);
    w.y = (short)f2bf(acc[ft][1]);
    w.z = (short)f2bf(acc[ft][2]);
    w.w = (short)f2bf(acc[ft][3]);
    *(short4*)&kvb[(ft * 16 + lc) * DD + e0] = w;
  }
}

// ---------------- k2: exclusive prefix scan over chunks ----------------
__global__ __launch_bounds__(256) void k2_scan(float* __restrict__ ksum,
                                               unsigned short* __restrict__ kvws) {
  const int blk = blockIdx.x;      // 32*9
  const int bh = blk / 9, part = blk % 9;
  const int t = threadIdx.x;
  if (part < 8) {
    unsigned* p = (unsigned*)kvws;
    size_t off = (size_t)bh * NC * 2048 + part * 256 + t;
    float a0 = 0.f, a1 = 0.f;
    for (int c = 0; c < NC; ++c) {
      unsigned x = p[off + (size_t)c * 2048];
      float x0 = bf2f((unsigned short)(x & 0xffffu));
      float x1 = bf2f((unsigned short)(x >> 16));
      unsigned w = (unsigned)f2bf(a0) | ((unsigned)f2bf(a1) << 16);
      p[off + (size_t)c * 2048] = w;
      a0 += x0; a1 += x1;
    }
  } else if (t < DD) {
    float run = 0.f;
    size_t off = (size_t)bh * NC * DD + t;
    for (int c = 0; c < NC; ++c) {
      float x = ksum[off + (size_t)c * DD];
      ksum[off + (size_t)c * DD] = run;
      run += x;
    }
  }
}

// ---------------- k3: output ----------------
__global__ __launch_bounds__(256) void k3_out(const float* __restrict__ qg,
                                              const float* __restrict__ kg,
                                              const float* __restrict__ vg,
                                              const float* __restrict__ partmax,
                                              const float* __restrict__ ksum,
                                              const unsigned short* __restrict__ kvws,
                                              float* __restrict__ out) {
  __shared__ __align__(16) unsigned short Kb[CH * 72];        // K' row-major [j][e]
  __shared__ __align__(16) unsigned short Vt[DD * 72];        // V^T [f][j]
  __shared__ __align__(16) unsigned short Sl[4][16 * 40];     // per-wave masked S (bf16)
  const int blk = blockIdx.x;
  const int bh = blk >> 5, c = blk & 31;
  const float km = load_km(partmax, bh);
  const float c1 = NRM * 1.4426950408889634f;
  const float c2k = -km * c1;
  const int t = threadIdx.x;
  const size_t base = ((size_t)bh * NSEQ + (size_t)c * CH) * DD;
  const float4* k4 = (const float4*)(kg + base);
  const float4* v4 = (const float4*)(vg + base);
  // stage K' (row-major, packed writes) and V^T (scatter)
#pragma unroll
  for (int r = 0; r < 4; ++r) {
    int idx4 = t + 256 * r;
    int j = idx4 >> 4, e0 = (idx4 & 15) << 2;
    float4 kk = k4[idx4];
    float kv0[4] = {kk.x, kk.y, kk.z, kk.w};
    short4 w;
    w.x = (short)f2bf(exp2f(kv0[0] * c1 + c2k) + EPSF);
    w.y = (short)f2bf(exp2f(kv0[1] * c1 + c2k) + EPSF);
    w.z = (short)f2bf(exp2f(kv0[2] * c1 + c2k) + EPSF);
    w.w = (short)f2bf(exp2f(kv0[3] * c1 + c2k) + EPSF);
    *(short4*)&Kb[j * 72 + e0] = w;
    float4 vv = v4[idx4];
    float vv0[4] = {vv.x, vv.y, vv.z, vv.w};
#pragma unroll
    for (int i = 0; i < 4; ++i) Vt[(e0 + i) * 72 + j] = f2bf(vv0[i]);
  }
  const int wr = t >> 6, l = t & 63, lg = l >> 4, lc = l & 15;
  // Q': row = wr*16+lc, cols kt*32 + lg*8 .. +7
  float qe[2][8];
  const float* qrow = qg + base + (size_t)(wr * 16 + lc) * DD;
#pragma unroll
  for (int kt = 0; kt < 2; ++kt) {
    float4 x = *(const float4*)(qrow + kt * 32 + lg * 8);
    float4 y = *(const float4*)(qrow + kt * 32 + lg * 8 + 4);
    qe[kt][0] = x.x; qe[kt][1] = x.y; qe[kt][2] = x.z; qe[kt][3] = x.w;
    qe[kt][4] = y.x; qe[kt][5] = y.y; qe[kt][6] = y.z; qe[kt][7] = y.w;
  }
  float qm = -1e30f;
#pragma unroll
  for (int kt = 0; kt < 2; ++kt)
#pragma unroll
    for (int i = 0; i < 8; ++i) qm = fmaxf(qm, qe[kt][i]);
  qm = fmaxf(qm, __shfl_xor(qm, 16, 64));
  qm = fmaxf(qm, __shfl_xor(qm, 32, 64));
  const float c2q = -qm * c1;
  bf16x8 qf[2];
  float dp = 0.f;
  const float* ksp = ksum + (size_t)blk * DD;
#pragma unroll
  for (int kt = 0; kt < 2; ++kt) {
    float4 s0 = *(const float4*)(ksp + kt * 32 + lg * 8);
    float4 s1 = *(const float4*)(ksp + kt * 32 + lg * 8 + 4);
    float ksv[8] = {s0.x, s0.y, s0.z, s0.w, s1.x, s1.y, s1.z, s1.w};
#pragma unroll
    for (int i = 0; i < 8; ++i) {
      float qv = exp2f(qe[kt][i] * c1 + c2q) + EPSF;
      dp += qv * (ksv[i] + EPSF);
      qf[kt][i] = (short)f2bf(qv);
    }
  }
  dp += __shfl_xor(dp, 16, 64);
  dp += __shfl_xor(dp, 32, 64);   // full-row q'.(ksum+EPS), on all 4 lane-groups
  __syncthreads();

  f32x4 o[4];
#pragma unroll
  for (int ft = 0; ft < 4; ++ft) o[ft] = (f32x4){0.f, 0.f, 0.f, 0.f};

  // O_pref: B fragments direct from global bf16 ws [blk][f][e]
  const unsigned short* kvb = kvws + (size_t)blk * (DD * DD);
#pragma unroll
  for (int kt = 0; kt < 2; ++kt) {
#pragma unroll
    for (int ft = 0; ft < 4; ++ft) {
      bf16x8 b = *(const bf16x8*)(kvb + (ft * 16 + lc) * DD + kt * 32 + lg * 8);
      o[ft] = __builtin_amdgcn_mfma_f32_16x16x32_bf16(qf[kt], b, o[ft], 0, 0, 0);
    }
  }

  // causal intra part
  float rs0 = 0.f, rs1 = 0.f, rs2 = 0.f, rs3 = 0.f;
  const int irow = wr * 16 + lg * 4;   // + reg
  const int ng = (wr >> 1) + 1;
  for (int g = 0; g < ng; ++g) {
#pragma unroll
    for (int cc = 0; cc < 2; ++cc) {
      const int ct = 2 * g + cc;
      bf16x8 kb0 = *(const bf16x8*)&Kb[(ct * 16 + lc) * 72 + lg * 8];
      bf16x8 kb1 = *(const bf16x8*)&Kb[(ct * 16 + lc) * 72 + 32 + lg * 8];
      f32x4 s = (f32x4){0.f, 0.f, 0.f, 0.f};
      s = __builtin_amdgcn_mfma_f32_16x16x32_bf16(qf[0], kb0, s, 0, 0, 0);
      s = __builtin_amdgcn_mfma_f32_16x16x32_bf16(qf[1], kb1, s, 0, 0, 0);
      const int j = ct * 16 + lc;
      float v0 = (j <= irow + 0) ? s[0] : 0.f;
      float v1 = (j <= irow + 1) ? s[1] : 0.f;
      float v2 = (j <= irow + 2) ? s[2] : 0.f;
      float v3 = (j <= irow + 3) ? s[3] : 0.f;
      rs0 += v0; rs1 += v1; rs2 += v2; rs3 += v3;
      unsigned short* sl = &Sl[wr][0];
      sl[(lg * 4 + 0) * 40 + cc * 16 + lc] = f2bf(v0);
      sl[(lg * 4 + 1) * 40 + cc * 16 + lc] = f2bf(v1);
      sl[(lg * 4 + 2) * 40 + cc * 16 + lc] = f2bf(v2);
      sl[(lg * 4 + 3) * 40 + cc * 16 + lc] = f2bf(v3);
    }
    // A fragment of masked S (wave-local; DS pipe is in-order within a wave)
    bf16x8 sa = *(const bf16x8*)&Sl[wr][lc * 40 + lg * 8];
#pragma unroll
    for (int ft = 0; ft < 4; ++ft) {
      bf16x8 vb = *(const bf16x8*)&Vt[(ft * 16 + lc) * 72 + g * 32 + lg * 8];
      o[ft] = __builtin_amdgcn_mfma_f32_16x16x32_bf16(sa, vb, o[ft], 0, 0, 0);
    }
  }
  // rowsum reduce over the 16 columns (lanes within 16-group)
#pragma unroll
  for (int m = 1; m < 16; m <<= 1) {
    rs0 += __shfl_xor(rs0, m, 64);
    rs1 += __shfl_xor(rs1, m, 64);
    rs2 += __shfl_xor(rs2, m, 64);
    rs3 += __shfl_xor(rs3, m, 64);
  }
  float rsv[4] = {rs0, rs1, rs2, rs3};
  float* op = out + base;
#pragma unroll
  for (int reg = 0; reg < 4; ++reg) {
    float d = __shfl(dp, lg * 4 + reg, 64) + rsv[reg];
    float dinv = 1.0f / d;
#pragma unroll
    for (int ft = 0; ft < 4; ++ft) {
      op[(size_t)(irow + reg) * DD + ft * 16 + lc] = o[ft][reg] * dinv;
    }
  }
}

extern "C" void kernel_launch(void* const* d_in, const int* in_sizes, int n_in,
                              void* d_out, int out_size, void* d_ws, size_t ws_size,
                              hipStream_t stream) {
  const float* q = (const float*)d_in[0];
  const float* k = (const float*)d_in[1];
  const float* v = (const float*)d_in[2];
  float* out = (float*)d_out;
  // ws layout: partmax[256] f32 | ksum[32*32*64] f32 | kv bf16 [32*32*4096]
  float* partmax = (float*)d_ws;
  float* ksum = partmax + 256;
  unsigned short* kvws = (unsigned short*)(ksum + (size_t)BHN * NC * DD);

  hipLaunchKernelGGL(k0a_max, dim3(256), dim3(256), 0, stream, k, partmax);
  hipLaunchKernelGGL(k1_partial, dim3(BHN * NC), dim3(256), 0, stream,
                     k, v, partmax, ksum, kvws);
  hipLaunchKernelGGL(k2_scan, dim3(BHN * 9), dim3(256), 0, stream, ksum, kvws);
  hipLaunchKernelGGL(k3_out, dim3(BHN * NC), dim3(256), 0, stream,
                     q, k, v, partmax, ksum, kvws, out);
}

// Round 4
// 108.239 us; speedup vs baseline: 2.1441x; 1.0607x over previous
//
#include <hip/hip_runtime.h>

// Performer exp-kernel linear causal attention, MFMA bf16 version.
// B=4 H=8 N=2048 D=64 fp32 in/out.
// Stabilization maxes (q row-max, k global-max) CANCEL in num/denom ratio
// (EPS interaction ~5e-8 relative, far below bf16 noise) -> no max pass.
// k1 : per-chunk KV^T partials (bf16) + Ksum   (1024 blocks, MFMA)
// k2 : exclusive prefix scan over 32 chunks    (264 blocks, register scan)
// k3 : out = (Q'.KVpref + masked(Q'K'^T).V) / denom  (1024 blocks, MFMA)

#define NSEQ 2048
#define DD 64
#define CH 64
#define NC (NSEQ / CH)   // 32
#define BHN 32
#define EPSF 1e-8f
#define NRM 0.35355339059327373f   // 64^(-0.25)
#define C1 (NRM * 1.4426950408889634f)   // nrm * log2(e)

typedef short bf16x8 __attribute__((ext_vector_type(8)));
typedef float f32x4 __attribute__((ext_vector_type(4)));

__device__ __forceinline__ unsigned short f2bf(float f) {
  union { float f; unsigned u; } c; c.f = f;
  unsigned u = c.u + 0x7fffu + ((c.u >> 16) & 1u);
  return (unsigned short)(u >> 16);
}
__device__ __forceinline__ float bf2f(unsigned short s) {
  union { unsigned u; float f; } c; c.u = ((unsigned)s) << 16;
  return c.f;
}

// ---------------- k1: per-chunk KV partial (bf16) + Ksum ----------------
__global__ __launch_bounds__(256) void k1_partial(const float* __restrict__ kg,
                                                  const float* __restrict__ vg,
                                                  float* __restrict__ ksum,
                                                  unsigned short* __restrict__ kvws) {
  __shared__ __align__(16) unsigned short Kt[DD * 72];   // K'^T  [e][j]
  __shared__ __align__(16) unsigned short Vt[DD * 72];   // V^T   [f][j]
  const int blk = blockIdx.x;
  const int bh = blk >> 5, c = blk & 31;
  const int t = threadIdx.x;
  const size_t base = ((size_t)bh * NSEQ + (size_t)c * CH) * DD;
  const float4* k4 = (const float4*)(kg + base);
  const float4* v4 = (const float4*)(vg + base);
#pragma unroll
  for (int r = 0; r < 4; ++r) {
    int idx4 = t + 256 * r;
    int j = idx4 >> 4, e0 = (idx4 & 15) << 2;
    float4 kk = k4[idx4];
    float kv0[4] = {kk.x, kk.y, kk.z, kk.w};
    float4 vv = v4[idx4];
    float vv0[4] = {vv.x, vv.y, vv.z, vv.w};
#pragma unroll
    for (int i = 0; i < 4; ++i) {
      Kt[(e0 + i) * 72 + j] = f2bf(exp2f(kv0[i] * C1) + EPSF);
      Vt[(e0 + i) * 72 + j] = f2bf(vv0[i]);
    }
  }
  __syncthreads();
  const int wr = t >> 6, l = t & 63, lg = l >> 4, lc = l & 15;
  // A fragments: rows e = wr*16+lc, k = j
  bf16x8 a0 = *(const bf16x8*)&Kt[(wr * 16 + lc) * 72 + lg * 8];
  bf16x8 a1 = *(const bf16x8*)&Kt[(wr * 16 + lc) * 72 + 32 + lg * 8];
  // Ksum over j of K'[j][e]: this lane holds 16 j-values of row e
  float ks = 0.f;
#pragma unroll
  for (int i = 0; i < 8; ++i) ks += bf2f((unsigned short)a0[i]) + bf2f((unsigned short)a1[i]);
  ks += __shfl_xor(ks, 16, 64);
  ks += __shfl_xor(ks, 32, 64);
  if (lg == 0) ksum[(size_t)blk * DD + wr * 16 + lc] = ks;
  // KV = K'^T @ V
  f32x4 acc[4];
#pragma unroll
  for (int ft = 0; ft < 4; ++ft) { acc[ft] = (f32x4){0.f, 0.f, 0.f, 0.f}; }
#pragma unroll
  for (int ft = 0; ft < 4; ++ft) {
    bf16x8 b0 = *(const bf16x8*)&Vt[(ft * 16 + lc) * 72 + lg * 8];
    bf16x8 b1 = *(const bf16x8*)&Vt[(ft * 16 + lc) * 72 + 32 + lg * 8];
    acc[ft] = __builtin_amdgcn_mfma_f32_16x16x32_bf16(a0, b0, acc[ft], 0, 0, 0);
    acc[ft] = __builtin_amdgcn_mfma_f32_16x16x32_bf16(a1, b1, acc[ft], 0, 0, 0);
  }
  // store f-major bf16: ws[blk][f][e]; rows e = wr*16 + lg*4 + reg (4 consecutive)
  unsigned short* kvb = kvws + (size_t)blk * (DD * DD);
  const int e0 = wr * 16 + lg * 4;
#pragma unroll
  for (int ft = 0; ft < 4; ++ft) {
    short4 w;
    w.x = (short)f2bf(acc[ft][0]);
    w.y = (short)f2bf(acc[ft][1]);
    w.z = (short)f2bf(acc[ft][2]);
    w.w = (short)f2bf(acc[ft][3]);
    *(short4*)&kvb[(ft * 16 + lc) * DD + e0] = w;
  }
}

// ---------------- k2: exclusive prefix scan over chunks (register scan) ----------------
// blocks 0..255: kv columns. Each thread owns one dword column of one bh:
//   loads all 32 chunk values into registers (loads overlap), scans, writes back.
// blocks 256..263: ksum scan, one thread per (bh, e).
__global__ __launch_bounds__(256) void k2_scan(float* __restrict__ ksum,
                                               unsigned short* __restrict__ kvws) {
  const int blk = blockIdx.x;
  const int t = threadIdx.x;
  if (blk < 256) {
    const int bh = blk >> 3;
    const int col = (blk & 7) * 256 + t;   // dword col 0..2047
    unsigned* p = (unsigned*)kvws + (size_t)bh * NC * 2048 + col;
    unsigned x[NC];
#pragma unroll
    for (int c = 0; c < NC; ++c) x[c] = p[(size_t)c * 2048];
    float a0 = 0.f, a1 = 0.f;
#pragma unroll
    for (int c = 0; c < NC; ++c) {
      float x0 = bf2f((unsigned short)(x[c] & 0xffffu));
      float x1 = bf2f((unsigned short)(x[c] >> 16));
      p[(size_t)c * 2048] = (unsigned)f2bf(a0) | ((unsigned)f2bf(a1) << 16);
      a0 += x0; a1 += x1;
    }
  } else {
    const int gid = (blk - 256) * 256 + t;   // 0..2047
    const int bh = gid >> 6, e = gid & 63;
    float* pk = ksum + (size_t)bh * NC * DD + e;
    float x[NC];
#pragma unroll
    for (int c = 0; c < NC; ++c) x[c] = pk[(size_t)c * DD];
    float run = 0.f;
#pragma unroll
    for (int c = 0; c < NC; ++c) { pk[(size_t)c * DD] = run; run += x[c]; }
  }
}

// ---------------- k3: output ----------------
__global__ __launch_bounds__(256) void k3_out(const float* __restrict__ qg,
                                              const float* __restrict__ kg,
                                              const float* __restrict__ vg,
                                              const float* __restrict__ ksum,
                                              const unsigned short* __restrict__ kvws,
                                              float* __restrict__ out) {
  __shared__ __align__(16) unsigned short Kb[CH * 72];        // K' row-major [j][e]
  __shared__ __align__(16) unsigned short Vt[DD * 72];        // V^T [f][j]
  __shared__ __align__(16) unsigned short Sl[4][16 * 40];     // per-wave masked S (bf16)
  const int blk = blockIdx.x;
  const int t = threadIdx.x;
  const size_t base = (size_t)blk * (CH * DD);
  const float4* k4 = (const float4*)(kg + base);
  const float4* v4 = (const float4*)(vg + base);
  // stage K' (row-major, packed writes) and V^T (scatter)
#pragma unroll
  for (int r = 0; r < 4; ++r) {
    int idx4 = t + 256 * r;
    int j = idx4 >> 4, e0 = (idx4 & 15) << 2;
    float4 kk = k4[idx4];
    float kv0[4] = {kk.x, kk.y, kk.z, kk.w};
    short4 w;
    w.x = (short)f2bf(exp2f(kv0[0] * C1) + EPSF);
    w.y = (short)f2bf(exp2f(kv0[1] * C1) + EPSF);
    w.z = (short)f2bf(exp2f(kv0[2] * C1) + EPSF);
    w.w = (short)f2bf(exp2f(kv0[3] * C1) + EPSF);
    *(short4*)&Kb[j * 72 + e0] = w;
    float4 vv = v4[idx4];
    float vv0[4] = {vv.x, vv.y, vv.z, vv.w};
#pragma unroll
    for (int i = 0; i < 4; ++i) Vt[(e0 + i) * 72 + j] = f2bf(vv0[i]);
  }
  const int wr = t >> 6, l = t & 63, lg = l >> 4, lc = l & 15;
  // Q': row = wr*16+lc, cols kt*32 + lg*8 .. +7
  float qe[2][8];
  const float* qrow = qg + base + (size_t)(wr * 16 + lc) * DD;
#pragma unroll
  for (int kt = 0; kt < 2; ++kt) {
    float4 x = *(const float4*)(qrow + kt * 32 + lg * 8);
    float4 y = *(const float4*)(qrow + kt * 32 + lg * 8 + 4);
    qe[kt][0] = x.x; qe[kt][1] = x.y; qe[kt][2] = x.z; qe[kt][3] = x.w;
    qe[kt][4] = y.x; qe[kt][5] = y.y; qe[kt][6] = y.z; qe[kt][7] = y.w;
  }
  bf16x8 qf[2];
  float dp = 0.f;
  const float* ksp = ksum + (size_t)blk * DD;
#pragma unroll
  for (int kt = 0; kt < 2; ++kt) {
    float4 s0 = *(const float4*)(ksp + kt * 32 + lg * 8);
    float4 s1 = *(const float4*)(ksp + kt * 32 + lg * 8 + 4);
    float ksv[8] = {s0.x, s0.y, s0.z, s0.w, s1.x, s1.y, s1.z, s1.w};
#pragma unroll
    for (int i = 0; i < 8; ++i) {
      float qv = exp2f(qe[kt][i] * C1) + EPSF;
      dp += qv * (ksv[i] + EPSF);
      qf[kt][i] = (short)f2bf(qv);
    }
  }
  dp += __shfl_xor(dp, 16, 64);
  dp += __shfl_xor(dp, 32, 64);   // full-row q'.(ksum+EPS), on all 4 lane-groups
  __syncthreads();

  f32x4 o[4];
#pragma unroll
  for (int ft = 0; ft < 4; ++ft) o[ft] = (f32x4){0.f, 0.f, 0.f, 0.f};

  // O_pref: B fragments direct from global bf16 ws [blk][f][e]
  const unsigned short* kvb = kvws + (size_t)blk * (DD * DD);
#pragma unroll
  for (int kt = 0; kt < 2; ++kt) {
#pragma unroll
    for (int ft = 0; ft < 4; ++ft) {
      bf16x8 b = *(const bf16x8*)(kvb + (ft * 16 + lc) * DD + kt * 32 + lg * 8);
      o[ft] = __builtin_amdgcn_mfma_f32_16x16x32_bf16(qf[kt], b, o[ft], 0, 0, 0);
    }
  }

  // causal intra part
  float rs0 = 0.f, rs1 = 0.f, rs2 = 0.f, rs3 = 0.f;
  const int irow = wr * 16 + lg * 4;   // + reg
  const int ng = (wr >> 1) + 1;
  for (int g = 0; g < ng; ++g) {
#pragma unroll
    for (int cc = 0; cc < 2; ++cc) {
      const int ct = 2 * g + cc;
      bf16x8 kb0 = *(const bf16x8*)&Kb[(ct * 16 + lc) * 72 + lg * 8];
      bf16x8 kb1 = *(const bf16x8*)&Kb[(ct * 16 + lc) * 72 + 32 + lg * 8];
      f32x4 s = (f32x4){0.f, 0.f, 0.f, 0.f};
      s = __builtin_amdgcn_mfma_f32_16x16x32_bf16(qf[0], kb0, s, 0, 0, 0);
      s = __builtin_amdgcn_mfma_f32_16x16x32_bf16(qf[1], kb1, s, 0, 0, 0);
      const int j = ct * 16 + lc;
      float v0 = (j <= irow + 0) ? s[0] : 0.f;
      float v1 = (j <= irow + 1) ? s[1] : 0.f;
      float v2 = (j <= irow + 2) ? s[2] : 0.f;
      float v3 = (j <= irow + 3) ? s[3] : 0.f;
      rs0 += v0; rs1 += v1; rs2 += v2; rs3 += v3;
      unsigned short* sl = &Sl[wr][0];
      sl[(lg * 4 + 0) * 40 + cc * 16 + lc] = f2bf(v0);
      sl[(lg * 4 + 1) * 40 + cc * 16 + lc] = f2bf(v1);
      sl[(lg * 4 + 2) * 40 + cc * 16 + lc] = f2bf(v2);
      sl[(lg * 4 + 3) * 40 + cc * 16 + lc] = f2bf(v3);
    }
    // A fragment of masked S (wave-local; DS pipe is in-order within a wave)
    bf16x8 sa = *(const bf16x8*)&Sl[wr][lc * 40 + lg * 8];
#pragma unroll
    for (int ft = 0; ft < 4; ++ft) {
      bf16x8 vb = *(const bf16x8*)&Vt[(ft * 16 + lc) * 72 + g * 32 + lg * 8];
      o[ft] = __builtin_amdgcn_mfma_f32_16x16x32_bf16(sa, vb, o[ft], 0, 0, 0);
    }
  }
  // rowsum reduce over the 16 columns (lanes within 16-group)
#pragma unroll
  for (int m = 1; m < 16; m <<= 1) {
    rs0 += __shfl_xor(rs0, m, 64);
    rs1 += __shfl_xor(rs1, m, 64);
    rs2 += __shfl_xor(rs2, m, 64);
    rs3 += __shfl_xor(rs3, m, 64);
  }
  float rsv[4] = {rs0, rs1, rs2, rs3};
  float* op = out + base;
#pragma unroll
  for (int reg = 0; reg < 4; ++reg) {
    float d = __shfl(dp, lg * 4 + reg, 64) + rsv[reg];
    float dinv = 1.0f / d;
#pragma unroll
    for (int ft = 0; ft < 4; ++ft) {
      op[(size_t)(irow + reg) * DD + ft * 16 + lc] = o[ft][reg] * dinv;
    }
  }
}

extern "C" void kernel_launch(void* const* d_in, const int* in_sizes, int n_in,
                              void* d_out, int out_size, void* d_ws, size_t ws_size,
                              hipStream_t stream) {
  const float* q = (const float*)d_in[0];
  const float* k = (const float*)d_in[1];
  const float* v = (const float*)d_in[2];
  float* out = (float*)d_out;
  // ws layout: ksum[32*32*64] f32 | kv bf16 [32*32*4096]
  float* ksum = (float*)d_ws;
  unsigned short* kvws = (unsigned short*)(ksum + (size_t)BHN * NC * DD);

  hipLaunchKernelGGL(k1_partial, dim3(BHN * NC), dim3(256), 0, stream,
                     k, v, ksum, kvws);
  hipLaunchKernelGGL(k2_scan, dim3(264), dim3(256), 0, stream, ksum, kvws);
  hipLaunchKernelGGL(k3_out, dim3(BHN * NC), dim3(256), 0, stream,
                     q, k, v, ksum, kvws, out);
}